// Round 2
// baseline (566.621 us; speedup 1.0000x reference)
//
#include <hip/hip_runtime.h>
#include <stdint.h>

#define T_SEQ 2048
#define HIDDEN 4096
#define NUM_HEADS 32
#define NUM_KV 8
#define HD 128
#define QSIZE (NUM_HEADS * HD)       /* 4096 */
#define KVSIZE (NUM_KV * HD)         /* 1024 */
#define QKV_N (QSIZE + 2 * KVSIZE)   /* 6144 */

typedef __attribute__((ext_vector_type(8))) __bf16 bf16x8;
typedef __attribute__((ext_vector_type(4))) float f32x4;

// ---------- helpers ----------
static __device__ __forceinline__ unsigned short f2bf(float f) {
  union { float f; unsigned int u; } v; v.f = f;
  unsigned int u = v.u;
  return (unsigned short)((u + 0x7FFFu + ((u >> 16) & 1u)) >> 16);
}

static __device__ __forceinline__ void async16(const void* g, void* l) {
  __builtin_amdgcn_global_load_lds((__attribute__((address_space(1))) void*)g,
                                   (__attribute__((address_space(3))) void*)l,
                                   16, 0, 0);
}

// ---------- fused fp32 -> bf16 cast of all three tensors ----------
#define N1 (T_SEQ * HIDDEN / 4)
#define N2 (QKV_N * HIDDEN / 4)
#define N3 (HIDDEN * QSIZE / 4)
__global__ void cvt_all(const float* __restrict__ h,
                        const float* __restrict__ wq,
                        const float* __restrict__ wo,
                        unsigned short* __restrict__ hb,
                        unsigned short* __restrict__ wqb,
                        unsigned short* __restrict__ wob) {
  int i = blockIdx.x * 256 + threadIdx.x;
  const float* src;
  unsigned short* dst;
  int j;
  if (i < N1) { src = h; dst = hb; j = i; }
  else if (i < N1 + N2) { src = wq; dst = wqb; j = i - N1; }
  else { src = wo; dst = wob; j = i - N1 - N2; }
  float4 f = ((const float4*)src)[j];
  ushort4 o;
  o.x = f2bf(f.x); o.y = f2bf(f.y); o.z = f2bf(f.z); o.w = f2bf(f.w);
  ((ushort4*)dst)[j] = o;
}

// ============================================================================
// 256x256xBK=64 8-phase GEMM  (C[M][N] = A[M][K] * Bt[N][K]^T, optional bias,
// optional split-K via blockIdx.y -> C0/C1).
//
// 512 threads = 8 waves as 2(M) x 4(N), interleaved wave tiles (see r0).
// LDS: 2 bufs x (A 256x64 + B 256x64) bf16 = 128 KiB, 1 block/CU.
// Swizzle: byte ^= ((row&7)<<4); linear global_load_lds dest + inverse-
// swizzled global source + swizzled ds_read (both-sides rule). Verified:
// SQ_LDS_BANK_CONFLICT == 0.
//
// Read schedule (balanced {8,4,8,4}, compiler-counted lgkm waits — NO manual
// lgkmcnt(0) drains; m97/r109: compiler emits counted waits between ds_read
// and first consuming MFMA, letting late reads complete under the MFMAs):
//  p0: read A0(t) (8) ; stage A1(t+1)        | bar | MFMA (mh0,nh0) | bar
//  p1: read B1(t) (4) ; stage A0(t+2)        | bar | MFMA (mh0,nh1) | bar
//  p2: read A1(t) (8) ; stage B0(t+2)        | bar | MFMA (mh1,nh0) | bar
//  p3: stage B1(t+2); vmcnt(6) | bar | read B0(t+1) (4) ; MFMA (mh1,nh1) | bar
//
// Ledger: VM6 at p3(t) retires through A1(t+1); in-order retirement covers
// B0(t+1) (staged p2(t-1)). The barrier after every wave's VM6 makes tile
// t+1 valid for ALL waves, so the p3 B0(t+1) read (pinned after the barrier
// by sched_barrier) is safe. b0v regs are free after p2's MFMA. Overwrite
// safety: every stage targets a region >=2 barriers past its last ds_read;
// SCB;BAR;SCB sandwiches keep all memory ops phase-contained.
// Prologue stages 7 halves, vmcnt(6), barrier, pre-reads b0v(tile0).
// Tail: t=NT-2 stages only A1(NT-1), drains vmcnt(0), still reads B0(NT-1);
// t=NT-1 stages nothing, no p3 read.
// ============================================================================
#define BAR  __builtin_amdgcn_s_barrier()
#define SCB  __builtin_amdgcn_sched_barrier(0)
#define VM6  asm volatile("s_waitcnt vmcnt(6)" ::: "memory")
#define VM0  asm volatile("s_waitcnt vmcnt(0)" ::: "memory")

#define ST_A(bn, h, tt) do { \
    const unsigned short* sp_ = aSrc + (size_t)(2*(h))*K64 + ((size_t)(tt) << 6); \
    async16(sp_, lA##bn + (h)*8192 + tid*8); \
    async16(sp_ + K64, lA##bn + (h)*8192 + 4096 + tid*8); \
  } while(0)
#define ST_B(bn, h, tt) do { \
    const unsigned short* sp_ = bSrc + (size_t)(2*(h))*K64 + ((size_t)(tt) << 6); \
    async16(sp_, lB##bn + (h)*8192 + tid*8); \
    async16(sp_ + K64, lB##bn + (h)*8192 + 4096 + tid*8); \
  } while(0)

#define LDA(bn, mf, kk) (*(const bf16x8*)((const char*)lA##bn + aRowB + (mf)*4096 + cOf##kk))
#define LDB(bn, nf, kk) (*(const bf16x8*)((const char*)lB##bn + bRowB + (nf)*8192 + cOf##kk))

#define MFMAQ(mb, nb, bvar) do { \
    _Pragma("unroll") \
    for (int mf_ = 0; mf_ < 4; ++mf_) { \
      _Pragma("unroll") \
      for (int nf_ = 0; nf_ < 2; ++nf_) { \
        acc[(mb)+mf_][(nb)+nf_] = __builtin_amdgcn_mfma_f32_16x16x32_bf16( \
            a[mf_][0], bvar[nf_][0], acc[(mb)+mf_][(nb)+nf_], 0, 0, 0); \
        acc[(mb)+mf_][(nb)+nf_] = __builtin_amdgcn_mfma_f32_16x16x32_bf16( \
            a[mf_][1], bvar[nf_][1], acc[(mb)+mf_][(nb)+nf_], 0, 0, 0); \
      } } } while(0)

// MODE: 0 = steady; 1 = t==NT-2 (stage A1 only, vmcnt(0), keep p3 read);
// 2 = last tile (no stages, no vmcnt, no p3 read).
#define TILE_STEP(tt, bn, obn, MODE) do { \
    /* ---- p0: read A0, stage A1(t+1) ---- */ \
    _Pragma("unroll") \
    for (int mf_ = 0; mf_ < 4; ++mf_) { a[mf_][0] = LDA(bn, mf_, 0); a[mf_][1] = LDA(bn, mf_, 1); } \
    if (MODE < 2) ST_A(obn, 1, (tt)+1); \
    SCB; BAR; SCB; \
    __builtin_amdgcn_s_setprio(1); MFMAQ(0, 0, b0v); __builtin_amdgcn_s_setprio(0); \
    SCB; BAR; SCB; \
    /* ---- p1: read B1, stage A0(t+2) ---- */ \
    b1v[0][0] = LDB(bn, 2, 0); b1v[0][1] = LDB(bn, 2, 1); \
    b1v[1][0] = LDB(bn, 3, 0); b1v[1][1] = LDB(bn, 3, 1); \
    if (MODE == 0) ST_A(bn, 0, (tt)+2); \
    SCB; BAR; SCB; \
    __builtin_amdgcn_s_setprio(1); MFMAQ(0, 2, b1v); __builtin_amdgcn_s_setprio(0); \
    SCB; BAR; SCB; \
    /* ---- p2: read A1, stage B0(t+2) ---- */ \
    _Pragma("unroll") \
    for (int mf_ = 0; mf_ < 4; ++mf_) { a[mf_][0] = LDA(bn, 4+mf_, 0); a[mf_][1] = LDA(bn, 4+mf_, 1); } \
    if (MODE == 0) ST_B(bn, 0, (tt)+2); \
    SCB; BAR; SCB; \
    __builtin_amdgcn_s_setprio(1); MFMAQ(4, 0, b0v); __builtin_amdgcn_s_setprio(0); \
    SCB; BAR; SCB; \
    /* ---- p3: stage B1(t+2), vmcnt, bar, read B0(t+1), MFMA ---- */ \
    if (MODE == 0) { ST_B(bn, 1, (tt)+2); VM6; } \
    else if (MODE == 1) { VM0; } \
    SCB; BAR; SCB; \
    if (MODE < 2) { \
      b0v[0][0] = LDB(obn, 0, 0); b0v[0][1] = LDB(obn, 0, 1); \
      b0v[1][0] = LDB(obn, 1, 0); b0v[1][1] = LDB(obn, 1, 1); \
    } \
    __builtin_amdgcn_s_setprio(1); MFMAQ(4, 2, b1v); __builtin_amdgcn_s_setprio(0); \
    SCB; BAR; SCB; \
  } while(0)

__global__ __launch_bounds__(512, 2) void gemm256(
    const unsigned short* __restrict__ A,
    const unsigned short* __restrict__ Bt,
    const float* __restrict__ bias,
    float* __restrict__ C0, float* __restrict__ C1,
    int N, int K, int kslice) {
  __shared__ unsigned short lA0[16384];
  __shared__ unsigned short lB0[16384];
  __shared__ unsigned short lA1[16384];
  __shared__ unsigned short lB1[16384];

  const int tid = threadIdx.x;
  const int wv = tid >> 6, lane = tid & 63;
  const int quad = lane >> 4, l16 = lane & 15;
  const int wr = wv >> 2, wc = wv & 3;

  // bijective XCD swizzle (gridDim.x % 8 == 0 for both launches)
  const int s = (blockIdx.x & 7) * (gridDim.x >> 3) + (blockIdx.x >> 3);
  const int row0 = (s & 7) << 8;
  const int col0 = (s >> 3) << 8;
  const int z = blockIdx.y;
  float* __restrict__ C = z ? C1 : C0;
  const size_t kofs = (size_t)z * kslice;

  const int NT = kslice >> 6;
  const size_t K64 = (size_t)K << 6;

  // staging: thread tid stages LDS bytes [tid*16, +16) linearly;
  // inverse-swizzled source: row = tid>>3, col = ((tid&7) ^ ((tid>>3)&7))*8
  const int srow = tid >> 3;
  const int scol = ((tid & 7) ^ (srow & 7)) << 3;
  const unsigned short* aSrc = A  + (size_t)(row0 + srow) * K + kofs + scol;
  const unsigned short* bSrc = Bt + (size_t)(col0 + srow) * K + kofs + scol;

  // swizzled read offsets: row r -> byte r*128 + ((kk*64 + quad*16) ^ ((l16&7)<<4))
  const int xorv = (l16 & 7) << 4;
  const int cOf0 = (quad * 16) ^ xorv;
  const int cOf1 = (64 + quad * 16) ^ xorv;
  const int aRowB = (wr * 16 + l16) * 128;
  const int bRowB = (wc * 16 + l16) * 128;

  f32x4 acc[8][4] = {};
  bf16x8 a[4][2], b0v[2][2], b1v[2][2];

  // prologue: tile0 (A0,B0,B1,A1) + tile1 (A0,B0,B1) = 7 halves, 14 loads
  ST_A(0, 0, 0); ST_B(0, 0, 0); ST_B(0, 1, 0); ST_A(0, 1, 0);
  ST_A(1, 0, 1); ST_B(1, 0, 1); ST_B(1, 1, 1);
  VM6;  // 14 outstanding -> wait to 6: tile0's 4 halves complete
  SCB; BAR; SCB;
  // pre-read b0v for tile 0 (B-half0 of buf 0)
  b0v[0][0] = LDB(0, 0, 0); b0v[0][1] = LDB(0, 0, 1);
  b0v[1][0] = LDB(0, 1, 0); b0v[1][1] = LDB(0, 1, 1);

  for (int t = 0; t < NT - 2; t += 2) {
    TILE_STEP(t,     0, 1, 0);
    TILE_STEP(t + 1, 1, 0, 0);
  }
  TILE_STEP(NT - 2, 0, 1, 1);
  TILE_STEP(NT - 1, 1, 0, 2);

  // epilogue: C/D frag layout col=l16, row=quad*4+reg
#pragma unroll
  for (int mf = 0; mf < 8; ++mf) {
    const int r0 = row0 + mf * 32 + wr * 16 + quad * 4;
#pragma unroll
    for (int nf = 0; nf < 4; ++nf) {
      const int c = col0 + nf * 64 + wc * 16 + l16;
      const float bv = bias ? bias[c] : 0.0f;
#pragma unroll
      for (int r = 0; r < 4; ++r)
        C[(size_t)(r0 + r) * N + c] = acc[mf][nf][r] + bv;
    }
  }
}

// ---------- out += partial (float4) ----------
__global__ void reduce_add(float* __restrict__ out,
                           const float* __restrict__ part, int n4) {
  int i = blockIdx.x * 256 + threadIdx.x;
  if (i >= n4) return;
  float4 a = ((const float4*)out)[i];
  float4 b = ((const float4*)part)[i];
  a.x += b.x; a.y += b.y; a.z += b.z; a.w += b.w;
  ((float4*)out)[i] = a;
}

// ---------- RMSNorm + RoPE, wave-per-head ----------
__global__ __launch_bounds__(256) void norm_rope(
    const float* __restrict__ qkv,
    const float* __restrict__ qw,
    const float* __restrict__ kw,
    unsigned short* __restrict__ q,
    unsigned short* __restrict__ k) {
  const int t = blockIdx.x;
  const int wave = threadIdx.x >> 6, lane = threadIdx.x & 63;
#pragma unroll
  for (int it = 0; it < 10; it++) {
    const int slot = it * 4 + wave;
    const bool isq = slot < 32;
    const float* src = qkv + (size_t)t * QKV_N +
                       (isq ? slot * HD : QSIZE + (slot - 32) * HD);
    const float x0 = src[lane];
    const float x1 = src[lane + 64];
    float ss = x0 * x0 + x1 * x1;
#pragma unroll
    for (int m = 32; m >= 1; m >>= 1) ss += __shfl_xor(ss, m, 64);
    const float rn = rsqrtf(ss * (1.0f / 128.0f) + 1e-5f);
    const float* w = isq ? qw : kw;
    const float y0 = x0 * rn * w[lane];
    const float y1 = x1 * rn * w[lane + 64];
    const float p = __shfl_xor(y0, 32, 64);
    const int j = lane & 31;
    const float inv = exp2f(-(float)j * (13.28771237954945f / 32.0f));
    float s, c;
    sincosf((float)t * inv, &s, &c);
    const float r0 = (lane < 32) ? (y0 * c - p * s) : (y0 * c + p * s);
    unsigned short* dst = isq ? q + ((size_t)slot * T_SEQ + t) * HD
                              : k + ((size_t)(slot - 32) * T_SEQ + t) * HD;
    dst[lane] = f2bf(r0);
    dst[lane + 64] = f2bf(y1);
  }
}

// ---------- V transpose: qkv_f32 v-slice -> Vt[kvh][d][T] bf16 ----------
__global__ __launch_bounds__(256) void transpose_v(
    const float* __restrict__ qkv, unsigned short* __restrict__ vt) {
  __shared__ unsigned short tile[64 * 136];
  const int kvh = blockIdx.x, tt = blockIdx.y;
  const int tid = threadIdx.x;
  {
    const int t_r = tid >> 2, d0 = (tid & 3) * 32;
    const float* src = qkv + (size_t)(tt * 64 + t_r) * QKV_N +
                       (QSIZE + KVSIZE) + kvh * HD + d0;
#pragma unroll
    for (int i = 0; i < 8; i++) {
      float4 f = ((const float4*)src)[i];
      unsigned short* dptr = tile + t_r * 136 + d0 + i * 4;
      dptr[0] = f2bf(f.x); dptr[1] = f2bf(f.y);
      dptr[2] = f2bf(f.z); dptr[3] = f2bf(f.w);
    }
  }
  __syncthreads();
  {
    const int d_r = tid >> 1, t0 = (tid & 1) * 32;
    unsigned short buf[32];
#pragma unroll
    for (int i = 0; i < 32; i++) buf[i] = tile[(t0 + i) * 136 + d_r];
    uint4* dst = (uint4*)(vt + ((size_t)kvh * HD + d_r) * T_SEQ + tt * 64 + t0);
#pragma unroll
    for (int i = 0; i < 4; i++) dst[i] = ((uint4*)buf)[i];
  }
}

// ---------- flash attention (causal, GQA 4:1) ----------
#define BC 32
#define KCH 528  /* K chunk: 4 rows x 128 elems + 16 pad */
#define VCH 528  /* V chunk: 16 d-rows x 32 keys + 16 pad */
#define PST 40   /* P row stride (32 keys + 8 pad) */
__global__ __launch_bounds__(256, 3) void attn_fwd(
    const unsigned short* __restrict__ Q,   // [32][2048][128]
    const unsigned short* __restrict__ K,   // [8][2048][128]
    const unsigned short* __restrict__ Vt,  // [8][128][2048]
    unsigned short* __restrict__ O) {       // [2048][4096]
  __shared__ unsigned short lds_k[2][8 * KCH];   // 2 x 8448 B
  __shared__ unsigned short lds_v[2][8 * VCH];   // 2 x 8448 B
  __shared__ unsigned short lds_p[4 * 32 * PST]; // 10240 B  (total 44032 B)

  const int bx = blockIdx.x;
  const int qb = 15 - (bx >> 5);  // LPT: largest-work blocks first
  const int h = bx & 31;
  const int kvh = h >> 2;
  const int tid = threadIdx.x, wave = tid >> 6, lane = tid & 63;
  const int quad = lane >> 4, l16 = lane & 15;
  const int q0 = qb * 128;
  const int mrow0 = q0 + wave * 32;

  bf16x8 qf[2][4];
#pragma unroll
  for (int m = 0; m < 2; m++) {
    const unsigned short* qp =
        Q + ((size_t)h * T_SEQ + mrow0 + m * 16 + l16) * HD + quad * 8;
#pragma unroll
    for (int c2 = 0; c2 < 4; c2++) qf[m][c2] = *(const bf16x8*)(qp + c2 * 32);
  }

  f32x4 o_acc[2][8] = {};
  float lrow[2][4] = {};
  const float l2e_s = 1.4426950408889634f * 0.08838834764831845f;
  const float FMAX = 129.0f;
  const unsigned short* kb = K + (size_t)kvh * T_SEQ * HD;
  const unsigned short* vtb = Vt + (size_t)kvh * HD * T_SEQ;
  unsigned short* pbase = lds_p + wave * 32 * PST;

  const int krr = lane >> 4, krd = (lane & 15) * 8;  // K: row-in-chunk, d
  const int vrr = lane >> 2, vrk = (lane & 3) * 8;   // V: d-row-in-chunk, key

  const int nkt = 4 * (qb + 1);

#pragma unroll
  for (int cc = 0; cc < 2; cc++) {
    const int c = wave + cc * 4;
    async16(kb + (size_t)(c * 4 + krr) * HD + krd, lds_k[0] + c * KCH + lane * 8);
    async16(vtb + (size_t)(c * 16 + vrr) * T_SEQ + vrk, lds_v[0] + c * VCH + lane * 8);
  }

  for (int kt = 0; kt < nkt; kt++) {
    const int cur = kt & 1;
    const int kbase = kt * BC;
    __syncthreads();
    if (kt + 1 < nkt) {
      const int nb = kbase + BC;
#pragma unroll
      for (int cc = 0; cc < 2; cc++) {
        const int c = wave + cc * 4;
        async16(kb + (size_t)(nb + c * 4 + krr) * HD + krd,
                lds_k[cur ^ 1] + c * KCH + lane * 8);
        async16(vtb + (size_t)(c * 16 + vrr) * T_SEQ + nb + vrk,
                lds_v[cur ^ 1] + c * VCH + lane * 8);
      }
    }

    if (kbase > mrow0 + 31) continue;

    f32x4 s[2][2] = {};
#pragma unroll
    for (int c2 = 0; c2 < 4; c2++) {
#pragma unroll
      for (int nt = 0; nt < 2; nt++) {
        bf16x8 kf = *(const bf16x8*)(lds_k[cur] + (nt * 4 + (l16 >> 2)) * KCH +
                                     (l16 & 3) * 128 + c2 * 32 + quad * 8);
        s[0][nt] = __builtin_amdgcn_mfma_f32_16x16x32_bf16(qf[0][c2], kf, s[0][nt], 0, 0, 0);
        s[1][nt] = __builtin_amdgcn_mfma_f32_16x16x32_bf16(qf[1][c2], kf, s[1][nt], 0, 0, 0);
      }
    }

    const bool domask = (kbase + 31 > mrow0);
#pragma unroll
    for (int m = 0; m < 2; m++) {
#pragma unroll
      for (int r = 0; r < 4; r++) {
        const int row = mrow0 + m * 16 + quad * 4 + r;
        float ps = 0.f;
        unsigned short* pw = pbase + (m * 16 + quad * 4 + r) * PST + l16;
#pragma unroll
        for (int nt = 0; nt < 2; nt++) {
          float x = s[m][nt][r];
          if (domask && (kbase + nt * 16 + l16 > row)) x = -INFINITY;
          const float p = exp2f((x - FMAX) * l2e_s);
          ps += p;
          pw[nt * 16] = f2bf(p);
        }
        lrow[m][r] += ps;
      }
    }

    bf16x8 pa0 = *(const bf16x8*)(pbase + l16 * PST + quad * 8);
    bf16x8 pa1 = *(const bf16x8*)(pbase + (16 + l16) * PST + quad * 8);
#pragma unroll
    for (int dt = 0; dt < 8; dt++) {
      bf16x8 vf = *(const bf16x8*)(lds_v[cur] + dt * VCH + l16 * 32 + quad * 8);
      o_acc[0][dt] = __builtin_amdgcn_mfma_f32_16x16x32_bf16(pa0, vf, o_acc[0][dt], 0, 0, 0);
      o_acc[1][dt] = __builtin_amdgcn_mfma_f32_16x16x32_bf16(pa1, vf, o_acc[1][dt], 0, 0, 0);
    }
  }

#pragma unroll
  for (int m = 0; m < 2; m++) {
#pragma unroll
    for (int r = 0; r < 4; r++) {
      float l = lrow[m][r];
#pragma unroll
      for (int msk = 1; msk < 16; msk <<= 1) l += __shfl_xor(l, msk, 16);
      const float inv = 1.0f / l;
      const int row = mrow0 + m * 16 + quad * 4 + r;
#pragma unroll
      for (int dt = 0; dt < 8; dt++)
        O[(size_t)row * QSIZE + h * HD + dt * 16 + l16] =
            f2bf(o_acc[m][dt][r] * inv);
    }
  }
}

// ---------- launch ----------
extern "C" void kernel_launch(void* const* d_in, const int* in_sizes, int n_in,
                              void* d_out, int out_size, void* d_ws, size_t ws_size,
                              hipStream_t stream) {
  const float* hidden = (const float*)d_in[1];
  const float* w_qkv  = (const float*)d_in[2];
  const float* b_qkv  = (const float*)d_in[3];
  const float* q_norm = (const float*)d_in[4];
  const float* k_norm = (const float*)d_in[5];
  const float* w_o    = (const float*)d_in[6];
  float* out = (float*)d_out;

  char* ws = (char*)d_ws;
  unsigned short* hidden_bf = (unsigned short*)(ws + 0);          // 16 MB
  unsigned short* wqkv_bf   = (unsigned short*)(ws + 16777216);   // 48 MB
  unsigned short* wo_bf     = (unsigned short*)(ws + 67108864);   // 32 MB
  float*          qkv_f32   = (float*)(ws + 100663296);           // 48 MB
  unsigned short* q_bf      = (unsigned short*)(ws + 150994944);  // 16 MB
  unsigned short* k_bf      = (unsigned short*)(ws + 167772160);  // 4 MB
  unsigned short* vt_bf     = (unsigned short*)(ws + 171966464);  // 4 MB
  unsigned short* attn_bf   = (unsigned short*)(ws + 176160768);  // 16 MB
  float*          part_f32  = (float*)(ws + 100663296);           // 32 MB (aliases qkv_f32)

  cvt_all<<<(N1 + N2 + N3 + 255) / 256, 256, 0, stream>>>(
      hidden, w_qkv, w_o, hidden_bf, wqkv_bf, wo_bf);

  // QKV projection: M=2048 N=6144 K=4096, grid 8x24=192 blocks
  gemm256<<<dim3(192, 1), 512, 0, stream>>>(
      hidden_bf, wqkv_bf, b_qkv, qkv_f32, nullptr, QKV_N, HIDDEN, HIDDEN);

  norm_rope<<<dim3(T_SEQ), 256, 0, stream>>>(
      qkv_f32, q_norm, k_norm, q_bf, k_bf);

  transpose_v<<<dim3(8, T_SEQ / 64), 256, 0, stream>>>(qkv_f32, vt_bf);

  attn_fwd<<<dim3(512), 256, 0, stream>>>(q_bf, k_bf, vt_bf, attn_bf);

  // Output projection: M=2048 N=4096 K=4096, split-K=2 -> 8x16x2 = 256 blocks
  gemm256<<<dim3(128, 2), 512, 0, stream>>>(
      attn_bf, wo_bf, nullptr, out, part_f32, HIDDEN, QSIZE, QSIZE / 2);

  reduce_add<<<(T_SEQ * HIDDEN / 4 + 255) / 256, 256, 0, stream>>>(
      out, part_f32, T_SEQ * HIDDEN / 4);
}

// Round 3
// 547.684 us; speedup vs baseline: 1.0346x; 1.0346x over previous
//
#include <hip/hip_runtime.h>
#include <stdint.h>

#define T_SEQ 2048
#define HIDDEN 4096
#define NUM_HEADS 32
#define NUM_KV 8
#define HD 128
#define QSIZE (NUM_HEADS * HD)       /* 4096 */
#define KVSIZE (NUM_KV * HD)         /* 1024 */
#define QKV_N (QSIZE + 2 * KVSIZE)   /* 6144 */

typedef __attribute__((ext_vector_type(8))) __bf16 bf16x8;
typedef __attribute__((ext_vector_type(4))) float f32x4;

// ---------- helpers ----------
static __device__ __forceinline__ unsigned short f2bf(float f) {
  union { float f; unsigned int u; } v; v.f = f;
  unsigned int u = v.u;
  return (unsigned short)((u + 0x7FFFu + ((u >> 16) & 1u)) >> 16);
}

static __device__ __forceinline__ void async16(const void* g, void* l) {
  __builtin_amdgcn_global_load_lds((__attribute__((address_space(1))) void*)g,
                                   (__attribute__((address_space(3))) void*)l,
                                   16, 0, 0);
}

// ---------- fused fp32 -> bf16 cast of all three tensors ----------
#define N1 (T_SEQ * HIDDEN / 4)
#define N2 (QKV_N * HIDDEN / 4)
#define N3 (HIDDEN * QSIZE / 4)
__global__ void cvt_all(const float* __restrict__ h,
                        const float* __restrict__ wq,
                        const float* __restrict__ wo,
                        unsigned short* __restrict__ hb,
                        unsigned short* __restrict__ wqb,
                        unsigned short* __restrict__ wob) {
  int i = blockIdx.x * 256 + threadIdx.x;
  const float* src;
  unsigned short* dst;
  int j;
  if (i < N1) { src = h; dst = hb; j = i; }
  else if (i < N1 + N2) { src = wq; dst = wqb; j = i - N1; }
  else { src = wo; dst = wob; j = i - N1 - N2; }
  float4 f = ((const float4*)src)[j];
  ushort4 o;
  o.x = f2bf(f.x); o.y = f2bf(f.y); o.z = f2bf(f.z); o.w = f2bf(f.w);
  ((ushort4*)dst)[j] = o;
}

// ============================================================================
// 256 x (NFRAG*64) x BK=64 8-phase GEMM, C[M][N] = A[M][K]*Bt[N][K]^T.
// NFRAG=4: BN=256 (out-proj, r1-identical schedule). NFRAG=3: BN=192 so the
// QKV GEMM fills the grid exactly: 8 x 32 = 256 blocks on 256 CUs (was 192,
// 75% fill).
//
// 512 threads = 8 waves as 2(M) x 4(N), interleaved wave tiles. LDS =
// 2 bufs x (A 32 KiB + B NFRAG*8 KiB): 128 KiB (NFRAG=4) / 112 KiB (NFRAG=3),
// 1 block/CU. Swizzle byte ^= ((row&7)<<4), linear gload_lds dest +
// inverse-swizzled global source + swizzled ds_read (conflicts == 0).
//
// Phases per K-tile t (buf bn = t&1), r1-proven read map {12, 2(NFRAG-2), 8, 0}:
//  p0: read A0(8)+B01(4); stage A1(t+1)      | bar lgkm0 | MFMA (mh0,n01) | bar
//  p1: read Brest(2..4);  stage A0(t+2)      | bar lgkm0 | MFMA (mh0,nrest)| bar
//  p2: read A1(8);        stage Bu0[,Bu1](t+2)| bar lgkm0 | MFMA (mh1,n01) | bar
//  p3: stage Brest(t+2); vmcnt(NFRAG+2)      | bar lgkm0 | MFMA (mh1,nrest)| bar
//
// Ledger (loads/K-tile/thread = NFRAG+4): VM at p3(t) keeps the newest
// NFRAG+2 (= t+2's A0+all-B) and retires through A1(t+1) staged at p0(t) ->
// tile t+1 fully complete before any wave reads it (barrier after VM).
// Overwrite safety: every staged region's last ds_read is lgkm0-drained
// >= 1 barrier before the stage issues. Prologue: t0 all (NFRAG+4) + t1's
// A0+B (NFRAG+2), VM(NFRAG+2). Tail: t=NT-2 stages only A1(NT-1), VM0;
// t=NT-1 stages nothing.
// ============================================================================
#define BAR  __builtin_amdgcn_s_barrier()
#define SCB  __builtin_amdgcn_sched_barrier(0)
#define LGKM0 asm volatile("s_waitcnt lgkmcnt(0)" ::: "memory")
#define VM0  asm volatile("s_waitcnt vmcnt(0)" ::: "memory")
#define VMSS do { if (NFRAG == 4) asm volatile("s_waitcnt vmcnt(6)" ::: "memory"); \
                  else            asm volatile("s_waitcnt vmcnt(5)" ::: "memory"); } while(0)

#define ST_A(bn, h, tt) do { \
    const unsigned short* sp_ = aSrc + (size_t)(2*(h))*K64 + ((size_t)(tt) << 6); \
    async16(sp_, &lA[bn][(h)*8192 + tid*8]); \
    async16(sp_ + K64, &lA[bn][(h)*8192 + 4096 + tid*8]); \
  } while(0)
#define ST_BU(bn, u, tt) do { \
    const unsigned short* sp_ = bSrc + (size_t)(u)*K64 + ((size_t)(tt) << 6); \
    async16(sp_, &lB[bn][(u)*4096 + tid*8]); \
  } while(0)

#define LDAm(bn, mf, kk) (*(const bf16x8*)((const char*)lA[bn] + aRowB + (mf)*4096 + cOf##kk))
#define LDBm(bn, nf, kk) (*(const bf16x8*)((const char*)lB[bn] + bRowB + (nf)*8192 + cOf##kk))

#define MFMA_NH0(mb) do { \
    _Pragma("unroll") \
    for (int mf_ = 0; mf_ < 4; ++mf_) { \
      _Pragma("unroll") \
      for (int nf_ = 0; nf_ < 2; ++nf_) { \
        acc[(mb)+mf_][nf_] = __builtin_amdgcn_mfma_f32_16x16x32_bf16( \
            a[mf_][0], b0v[nf_][0], acc[(mb)+mf_][nf_], 0, 0, 0); \
        acc[(mb)+mf_][nf_] = __builtin_amdgcn_mfma_f32_16x16x32_bf16( \
            a[mf_][1], b0v[nf_][1], acc[(mb)+mf_][nf_], 0, 0, 0); \
      } } } while(0)

#define MFMA_NH1(mb) do { \
    _Pragma("unroll") \
    for (int mf_ = 0; mf_ < 4; ++mf_) { \
      _Pragma("unroll") \
      for (int nf_ = 0; nf_ < NFRAG - 2; ++nf_) { \
        acc[(mb)+mf_][2+nf_] = __builtin_amdgcn_mfma_f32_16x16x32_bf16( \
            a[mf_][0], b1v[nf_][0], acc[(mb)+mf_][2+nf_], 0, 0, 0); \
        acc[(mb)+mf_][2+nf_] = __builtin_amdgcn_mfma_f32_16x16x32_bf16( \
            a[mf_][1], b1v[nf_][1], acc[(mb)+mf_][2+nf_], 0, 0, 0); \
      } } } while(0)

// MODE: 0 = steady; 1 = t==NT-2 (stage A1 only, vmcnt(0)); 2 = last tile.
#define TILE_STEP(tt, bn, obn, MODE) do { \
    /* p0: read A0 + B01 ; stage A1(t+1) */ \
    _Pragma("unroll") \
    for (int mf_ = 0; mf_ < 4; ++mf_) { a[mf_][0] = LDAm(bn, mf_, 0); a[mf_][1] = LDAm(bn, mf_, 1); } \
    b0v[0][0] = LDBm(bn, 0, 0); b0v[0][1] = LDBm(bn, 0, 1); \
    b0v[1][0] = LDBm(bn, 1, 0); b0v[1][1] = LDBm(bn, 1, 1); \
    if (MODE < 2) ST_A(obn, 1, (tt)+1); \
    SCB; BAR; LGKM0; SCB; \
    __builtin_amdgcn_s_setprio(1); MFMA_NH0(0); __builtin_amdgcn_s_setprio(0); \
    SCB; BAR; SCB; \
    /* p1: read B rest ; stage A0(t+2) */ \
    _Pragma("unroll") \
    for (int nf_ = 0; nf_ < NFRAG - 2; ++nf_) { b1v[nf_][0] = LDBm(bn, 2+nf_, 0); b1v[nf_][1] = LDBm(bn, 2+nf_, 1); } \
    if (MODE == 0) ST_A(bn, 0, (tt)+2); \
    SCB; BAR; LGKM0; SCB; \
    __builtin_amdgcn_s_setprio(1); MFMA_NH1(0); __builtin_amdgcn_s_setprio(0); \
    SCB; BAR; SCB; \
    /* p2: read A1 ; stage B first part (t+2) */ \
    _Pragma("unroll") \
    for (int mf_ = 0; mf_ < 4; ++mf_) { a[mf_][0] = LDAm(bn, 4+mf_, 0); a[mf_][1] = LDAm(bn, 4+mf_, 1); } \
    if (MODE == 0) { ST_BU(bn, 0, (tt)+2); if (NFRAG == 4) ST_BU(bn, 1, (tt)+2); } \
    SCB; BAR; LGKM0; SCB; \
    __builtin_amdgcn_s_setprio(1); MFMA_NH0(4); __builtin_amdgcn_s_setprio(0); \
    SCB; BAR; SCB; \
    /* p3: stage B rest (t+2) ; vmcnt */ \
    if (MODE == 0) { \
      if (NFRAG == 4) { ST_BU(bn, 2, (tt)+2); ST_BU(bn, 3, (tt)+2); } \
      else            { ST_BU(bn, 1, (tt)+2); ST_BU(bn, 2, (tt)+2); } \
      VMSS; \
    } else if (MODE == 1) { VM0; } \
    SCB; BAR; LGKM0; SCB; \
    __builtin_amdgcn_s_setprio(1); MFMA_NH1(4); __builtin_amdgcn_s_setprio(0); \
    SCB; BAR; SCB; \
  } while(0)

template <int NFRAG>
__global__ __launch_bounds__(512, 2) void gemm256(
    const unsigned short* __restrict__ A,
    const unsigned short* __restrict__ Bt,
    const float* __restrict__ bias,
    float* __restrict__ C0, float* __restrict__ C1,
    int N, int K, int kslice) {
  __shared__ unsigned short lA[2][16384];
  __shared__ unsigned short lB[2][NFRAG * 4096];

  const int tid = threadIdx.x;
  const int wv = tid >> 6, lane = tid & 63;
  const int quad = lane >> 4, l16 = lane & 15;
  const int wr = wv >> 2, wc = wv & 3;

  // bijective XCD swizzle (gridDim.x % 8 == 0 for all launches)
  const int s = (blockIdx.x & 7) * (gridDim.x >> 3) + (blockIdx.x >> 3);
  const int row0 = (s & 7) << 8;
  const int col0 = (s >> 3) * (NFRAG * 64);
  const int z = blockIdx.y;
  float* __restrict__ C = z ? C1 : C0;
  const size_t kofs = (size_t)z * kslice;

  const int NT = kslice >> 6;
  const size_t K64 = (size_t)K << 6;

  // staging: thread tid stages LDS bytes [tid*16,+16) linearly; inverse-
  // swizzled source: row = tid>>3, col = ((tid&7) ^ ((tid>>3)&7))*8
  const int srow = tid >> 3;
  const int scol = ((tid & 7) ^ (srow & 7)) << 3;
  const unsigned short* aSrc = A  + (size_t)(row0 + srow) * K + kofs + scol;
  const unsigned short* bSrc = Bt + (size_t)(col0 + srow) * K + kofs + scol;

  // swizzled read offsets: row r -> byte r*128 + ((kk*64+quad*16) ^ ((l16&7)<<4))
  const int xorv = (l16 & 7) << 4;
  const int cOf0 = (quad * 16) ^ xorv;
  const int cOf1 = (64 + quad * 16) ^ xorv;
  const int aRowB = (wr * 16 + l16) * 128;
  const int bRowB = (wc * 16 + l16) * 128;

  f32x4 acc[8][NFRAG] = {};
  bf16x8 a[4][2], b0v[2][2], b1v[NFRAG - 2][2];

  // prologue: tile0 fully (NFRAG+4 loads) + tile1's A0+B (NFRAG+2 loads)
  ST_A(0, 0, 0);
#pragma unroll
  for (int u = 0; u < NFRAG; ++u) ST_BU(0, u, 0);
  ST_A(0, 1, 0);
  ST_A(1, 0, 1);
#pragma unroll
  for (int u = 0; u < NFRAG; ++u) ST_BU(1, u, 1);
  VMSS;  // retires tile0 completely; keeps tile1's NFRAG+2 in flight
  SCB; BAR; SCB;

  for (int t = 0; t < NT - 2; t += 2) {
    TILE_STEP(t,     0, 1, 0);
    TILE_STEP(t + 1, 1, 0, 0);
  }
  TILE_STEP(NT - 2, 0, 1, 1);
  TILE_STEP(NT - 1, 1, 0, 2);

  // epilogue: C/D frag layout col=l16, row=quad*4+reg
#pragma unroll
  for (int mf = 0; mf < 8; ++mf) {
    const int r0 = row0 + mf * 32 + wr * 16 + quad * 4;
#pragma unroll
    for (int nf = 0; nf < NFRAG; ++nf) {
      const int c = col0 + nf * 64 + wc * 16 + l16;
      const float bv = bias ? bias[c] : 0.0f;
#pragma unroll
      for (int r = 0; r < 4; ++r)
        C[(size_t)(r0 + r) * N + c] = acc[mf][nf][r] + bv;
    }
  }
}

// ---------- out += partial (float4) ----------
__global__ void reduce_add(float* __restrict__ out,
                           const float* __restrict__ part, int n4) {
  int i = blockIdx.x * 256 + threadIdx.x;
  if (i >= n4) return;
  float4 a = ((const float4*)out)[i];
  float4 b = ((const float4*)part)[i];
  a.x += b.x; a.y += b.y; a.z += b.z; a.w += b.w;
  ((float4*)out)[i] = a;
}

// ---------- RMSNorm + RoPE, wave-per-head ----------
__global__ __launch_bounds__(256) void norm_rope(
    const float* __restrict__ qkv,
    const float* __restrict__ qw,
    const float* __restrict__ kw,
    unsigned short* __restrict__ q,
    unsigned short* __restrict__ k) {
  const int t = blockIdx.x;
  const int wave = threadIdx.x >> 6, lane = threadIdx.x & 63;
#pragma unroll
  for (int it = 0; it < 10; it++) {
    const int slot = it * 4 + wave;
    const bool isq = slot < 32;
    const float* src = qkv + (size_t)t * QKV_N +
                       (isq ? slot * HD : QSIZE + (slot - 32) * HD);
    const float x0 = src[lane];
    const float x1 = src[lane + 64];
    float ss = x0 * x0 + x1 * x1;
#pragma unroll
    for (int m = 32; m >= 1; m >>= 1) ss += __shfl_xor(ss, m, 64);
    const float rn = rsqrtf(ss * (1.0f / 128.0f) + 1e-5f);
    const float* w = isq ? qw : kw;
    const float y0 = x0 * rn * w[lane];
    const float y1 = x1 * rn * w[lane + 64];
    const float p = __shfl_xor(y0, 32, 64);
    const int j = lane & 31;
    const float inv = exp2f(-(float)j * (13.28771237954945f / 32.0f));
    float s, c;
    sincosf((float)t * inv, &s, &c);
    const float r0 = (lane < 32) ? (y0 * c - p * s) : (y0 * c + p * s);
    unsigned short* dst = isq ? q + ((size_t)slot * T_SEQ + t) * HD
                              : k + ((size_t)(slot - 32) * T_SEQ + t) * HD;
    dst[lane] = f2bf(r0);
    dst[lane + 64] = f2bf(y1);
  }
}

// ---------- V transpose: qkv_f32 v-slice -> Vt[kvh][d][T] bf16 ----------
__global__ __launch_bounds__(256) void transpose_v(
    const float* __restrict__ qkv, unsigned short* __restrict__ vt) {
  __shared__ unsigned short tile[64 * 136];
  const int kvh = blockIdx.x, tt = blockIdx.y;
  const int tid = threadIdx.x;
  {
    const int t_r = tid >> 2, d0 = (tid & 3) * 32;
    const float* src = qkv + (size_t)(tt * 64 + t_r) * QKV_N +
                       (QSIZE + KVSIZE) + kvh * HD + d0;
#pragma unroll
    for (int i = 0; i < 8; i++) {
      float4 f = ((const float4*)src)[i];
      unsigned short* dptr = tile + t_r * 136 + d0 + i * 4;
      dptr[0] = f2bf(f.x); dptr[1] = f2bf(f.y);
      dptr[2] = f2bf(f.z); dptr[3] = f2bf(f.w);
    }
  }
  __syncthreads();
  {
    const int d_r = tid >> 1, t0 = (tid & 1) * 32;
    unsigned short buf[32];
#pragma unroll
    for (int i = 0; i < 32; i++) buf[i] = tile[(t0 + i) * 136 + d_r];
    uint4* dst = (uint4*)(vt + ((size_t)kvh * HD + d_r) * T_SEQ + tt * 64 + t0);
#pragma unroll
    for (int i = 0; i < 4; i++) dst[i] = ((uint4*)buf)[i];
  }
}

// ---------- flash attention (causal, GQA 4:1) ----------
#define BC 32
#define KCH 528  /* K chunk: 4 rows x 128 elems + 16 pad */
#define VCH 528  /* V chunk: 16 d-rows x 32 keys + 16 pad */
#define PST 40   /* P row stride (32 keys + 8 pad) */
__global__ __launch_bounds__(256, 3) void attn_fwd(
    const unsigned short* __restrict__ Q,   // [32][2048][128]
    const unsigned short* __restrict__ K,   // [8][2048][128]
    const unsigned short* __restrict__ Vt,  // [8][128][2048]
    unsigned short* __restrict__ O) {       // [2048][4096]
  __shared__ unsigned short lds_k[2][8 * KCH];   // 2 x 8448 B
  __shared__ unsigned short lds_v[2][8 * VCH];   // 2 x 8448 B
  __shared__ unsigned short lds_p[4 * 32 * PST]; // 10240 B  (total 44032 B)

  const int bx = blockIdx.x;
  const int qb = 15 - (bx >> 5);  // LPT: largest-work blocks first
  const int h = bx & 31;
  const int kvh = h >> 2;
  const int tid = threadIdx.x, wave = tid >> 6, lane = tid & 63;
  const int quad = lane >> 4, l16 = lane & 15;
  const int q0 = qb * 128;
  const int mrow0 = q0 + wave * 32;

  bf16x8 qf[2][4];
#pragma unroll
  for (int m = 0; m < 2; m++) {
    const unsigned short* qp =
        Q + ((size_t)h * T_SEQ + mrow0 + m * 16 + l16) * HD + quad * 8;
#pragma unroll
    for (int c2 = 0; c2 < 4; c2++) qf[m][c2] = *(const bf16x8*)(qp + c2 * 32);
  }

  f32x4 o_acc[2][8] = {};
  float lrow[2][4] = {};
  const float l2e_s = 1.4426950408889634f * 0.08838834764831845f;
  const float FMAX = 129.0f;
  const unsigned short* kb = K + (size_t)kvh * T_SEQ * HD;
  const unsigned short* vtb = Vt + (size_t)kvh * HD * T_SEQ;
  unsigned short* pbase = lds_p + wave * 32 * PST;

  const int krr = lane >> 4, krd = (lane & 15) * 8;  // K: row-in-chunk, d
  const int vrr = lane >> 2, vrk = (lane & 3) * 8;   // V: d-row-in-chunk, key

  const int nkt = 4 * (qb + 1);

#pragma unroll
  for (int cc = 0; cc < 2; cc++) {
    const int c = wave + cc * 4;
    async16(kb + (size_t)(c * 4 + krr) * HD + krd, lds_k[0] + c * KCH + lane * 8);
    async16(vtb + (size_t)(c * 16 + vrr) * T_SEQ + vrk, lds_v[0] + c * VCH + lane * 8);
  }

  for (int kt = 0; kt < nkt; kt++) {
    const int cur = kt & 1;
    const int kbase = kt * BC;
    __syncthreads();
    if (kt + 1 < nkt) {
      const int nb = kbase + BC;
#pragma unroll
      for (int cc = 0; cc < 2; cc++) {
        const int c = wave + cc * 4;
        async16(kb + (size_t)(nb + c * 4 + krr) * HD + krd,
                lds_k[cur ^ 1] + c * KCH + lane * 8);
        async16(vtb + (size_t)(c * 16 + vrr) * T_SEQ + nb + vrk,
                lds_v[cur ^ 1] + c * VCH + lane * 8);
      }
    }

    if (kbase > mrow0 + 31) continue;

    f32x4 s[2][2] = {};
#pragma unroll
    for (int c2 = 0; c2 < 4; c2++) {
#pragma unroll
      for (int nt = 0; nt < 2; nt++) {
        bf16x8 kf = *(const bf16x8*)(lds_k[cur] + (nt * 4 + (l16 >> 2)) * KCH +
                                     (l16 & 3) * 128 + c2 * 32 + quad * 8);
        s[0][nt] = __builtin_amdgcn_mfma_f32_16x16x32_bf16(qf[0][c2], kf, s[0][nt], 0, 0, 0);
        s[1][nt] = __builtin_amdgcn_mfma_f32_16x16x32_bf16(qf[1][c2], kf, s[1][nt], 0, 0, 0);
      }
    }

    const bool domask = (kbase + 31 > mrow0);
#pragma unroll
    for (int m = 0; m < 2; m++) {
#pragma unroll
      for (int r = 0; r < 4; r++) {
        const int row = mrow0 + m * 16 + quad * 4 + r;
        float ps = 0.f;
        unsigned short* pw = pbase + (m * 16 + quad * 4 + r) * PST + l16;
#pragma unroll
        for (int nt = 0; nt < 2; nt++) {
          float x = s[m][nt][r];
          if (domask && (kbase + nt * 16 + l16 > row)) x = -INFINITY;
          const float p = exp2f((x - FMAX) * l2e_s);
          ps += p;
          pw[nt * 16] = f2bf(p);
        }
        lrow[m][r] += ps;
      }
    }

    bf16x8 pa0 = *(const bf16x8*)(pbase + l16 * PST + quad * 8);
    bf16x8 pa1 = *(const bf16x8*)(pbase + (16 + l16) * PST + quad * 8);
#pragma unroll
    for (int dt = 0; dt < 8; dt++) {
      bf16x8 vf = *(const bf16x8*)(lds_v[cur] + dt * VCH + l16 * 32 + quad * 8);
      o_acc[0][dt] = __builtin_amdgcn_mfma_f32_16x16x32_bf16(pa0, vf, o_acc[0][dt], 0, 0, 0);
      o_acc[1][dt] = __builtin_amdgcn_mfma_f32_16x16x32_bf16(pa1, vf, o_acc[1][dt], 0, 0, 0);
    }
  }

#pragma unroll
  for (int m = 0; m < 2; m++) {
#pragma unroll
    for (int r = 0; r < 4; r++) {
      float l = lrow[m][r];
#pragma unroll
      for (int msk = 1; msk < 16; msk <<= 1) l += __shfl_xor(l, msk, 16);
      const float inv = 1.0f / l;
      const int row = mrow0 + m * 16 + quad * 4 + r;
#pragma unroll
      for (int dt = 0; dt < 8; dt++)
        O[(size_t)row * QSIZE + h * HD + dt * 16 + l16] =
            f2bf(o_acc[m][dt][r] * inv);
    }
  }
}

// ---------- launch ----------
extern "C" void kernel_launch(void* const* d_in, const int* in_sizes, int n_in,
                              void* d_out, int out_size, void* d_ws, size_t ws_size,
                              hipStream_t stream) {
  const float* hidden = (const float*)d_in[1];
  const float* w_qkv  = (const float*)d_in[2];
  const float* b_qkv  = (const float*)d_in[3];
  const float* q_norm = (const float*)d_in[4];
  const float* k_norm = (const float*)d_in[5];
  const float* w_o    = (const float*)d_in[6];
  float* out = (float*)d_out;

  char* ws = (char*)d_ws;
  unsigned short* hidden_bf = (unsigned short*)(ws + 0);          // 16 MB
  unsigned short* wqkv_bf   = (unsigned short*)(ws + 16777216);   // 48 MB
  unsigned short* wo_bf     = (unsigned short*)(ws + 67108864);   // 32 MB
  float*          qkv_f32   = (float*)(ws + 100663296);           // 48 MB
  unsigned short* q_bf      = (unsigned short*)(ws + 150994944);  // 16 MB
  unsigned short* k_bf      = (unsigned short*)(ws + 167772160);  // 4 MB
  unsigned short* vt_bf     = (unsigned short*)(ws + 171966464);  // 4 MB
  unsigned short* attn_bf   = (unsigned short*)(ws + 176160768);  // 16 MB
  float*          part_f32  = (float*)(ws + 100663296);           // 32 MB (aliases qkv_f32)

  cvt_all<<<(N1 + N2 + N3 + 255) / 256, 256, 0, stream>>>(
      hidden, w_qkv, w_o, hidden_bf, wqkv_bf, wo_bf);

  // QKV projection: M=2048 N=6144 K=4096. BN=192 -> grid 8x32 = 256 blocks
  // (exact CU fill; was 192 blocks = 75%).
  gemm256<3><<<dim3(256, 1), 512, 0, stream>>>(
      hidden_bf, wqkv_bf, b_qkv, qkv_f32, nullptr, QKV_N, HIDDEN, HIDDEN);

  norm_rope<<<dim3(T_SEQ), 256, 0, stream>>>(
      qkv_f32, q_norm, k_norm, q_bf, k_bf);

  transpose_v<<<dim3(8, T_SEQ / 64), 256, 0, stream>>>(qkv_f32, vt_bf);

  attn_fwd<<<dim3(512), 256, 0, stream>>>(q_bf, k_bf, vt_bf, attn_bf);

  // Output projection: M=2048 N=4096 K=4096, split-K=2 -> 8x16x2 = 256 blocks
  gemm256<4><<<dim3(128, 2), 512, 0, stream>>>(
      attn_bf, wo_bf, nullptr, out, part_f32, HIDDEN, QSIZE, QSIZE / 2);

  reduce_add<<<(T_SEQ * HIDDEN / 4 + 255) / 256, 256, 0, stream>>>(
      out, part_f32, T_SEQ * HIDDEN / 4);
}